// Round 7
// baseline (477.540 us; speedup 1.0000x reference)
//
#include <hip/hip_runtime.h>
#include <hip/hip_bf16.h>

typedef unsigned short u16;
typedef __attribute__((ext_vector_type(8))) short s8v;   // 8 bf16 (4 VGPRs) MFMA A/B frag
typedef __attribute__((ext_vector_type(4))) float f4v;   // MFMA C/D frag

#define Bb 4
#define Ss 2048
#define Dd 1024
#define Rr 512
#define Hh 8
#define DHd 64
#define Mm 8192   // B*S

__device__ __forceinline__ float bf2f(u16 u){
    union { unsigned int i; float f; } v; v.i = ((unsigned int)u)<<16; return v.f;
}
__device__ __forceinline__ u16 f2bf(float f){
    __hip_bfloat16 h = __float2bfloat16(f);
    return *(u16*)&h;
}
__device__ __forceinline__ void gld_lds16(const u16* g, u16* l){
    // async global->LDS, 16B/lane; LDS dest = (wave-uniform base) + lane*16
    __builtin_amdgcn_global_load_lds((const __attribute__((address_space(1))) unsigned int*)g,
                                     (__attribute__((address_space(3))) unsigned int*)l, 16, 0, 0);
}

// ---------------- fp32 -> bf16 bulk convert ----------------
__global__ __launch_bounds__(256) void k_f2b(
    const float* __restrict__ in, u16* __restrict__ out)
{
    const size_t i = (size_t)blockIdx.x*256 + threadIdx.x;
    float4 v = ((const float4*)in)[i];
    ushort4 o;
    o.x = f2bf(v.x); o.y = f2bf(v.y); o.z = f2bf(v.z); o.w = f2bf(v.w);
    ((ushort4*)out)[i] = o;
}

// ---------------- transpose + convert: src[n][A][B] f32 -> dst[n][B][A] bf16 ----------------
__global__ __launch_bounds__(256) void k_transpose_f2b(
    const float* __restrict__ src, u16* __restrict__ dst, int A, int B)
{
    __shared__ float t[64][65];
    const int a0 = blockIdx.x*64, b0 = blockIdx.y*64, n = blockIdx.z;
    const size_t sbase = (size_t)n*A*B;
    const int r = threadIdx.x>>4, c = threadIdx.x&15;
#pragma unroll
    for (int p=0;p<4;p++){
        const int ar = r + p*16;
        float4 v = *(const float4*)(src + sbase + (size_t)(a0+ar)*B + b0 + c*4);
        t[ar][c*4+0]=v.x; t[ar][c*4+1]=v.y; t[ar][c*4+2]=v.z; t[ar][c*4+3]=v.w;
    }
    __syncthreads();
#pragma unroll
    for (int p=0;p<4;p++){
        const int br = r + p*16;
        ushort4 o;
        o.x = f2bf(t[c*4+0][br]); o.y = f2bf(t[c*4+1][br]);
        o.z = f2bf(t[c*4+2][br]); o.w = f2bf(t[c*4+3][br]);
        *(ushort4*)(dst + sbase + (size_t)(b0+br)*A + a0 + c*4) = o;
    }
}

// ---------------- V transpose: vb [M][R] bf16 -> vtb [BH][DH][S] bf16 ----------------
__global__ __launch_bounds__(256) void k_transpose_v(
    const u16* __restrict__ vb, u16* __restrict__ vtb)
{
    __shared__ u16 T[64][72];   // row stride 144B (16B-aligned)
    const int st = blockIdx.x, bh = blockIdx.y;
    const int b = bh>>3, h = bh&7;
    const int tid = threadIdx.x;
    const int srow = tid>>2, c4 = tid&3;
#pragma unroll
    for (int p=0;p<2;p++){
        const int ch = c4 + p*4;
        s8v v = *(const s8v*)(vb + (size_t)(b*Ss + st*64 + srow)*Rr + h*DHd + ch*8);
        *(s8v*)&T[srow][ch*8] = v;
    }
    __syncthreads();
    const int dl = tid & 63, w2 = tid>>6;
#pragma unroll
    for (int p=0;p<2;p++){
        const int sc = w2*2 + p;
        u16 o[8];
#pragma unroll
        for (int j=0;j<8;j++) o[j] = T[sc*8+j][dl];
        *(s8v*)(vtb + (size_t)bh*DHd*Ss + (size_t)dl*Ss + st*64 + sc*8) = *(s8v*)o;
    }
}

// ---------------- q/k/v router softmax weights [M,8] each (fp32 in) ----------------
__global__ __launch_bounds__(64) void k_router_qkv(
    const float* __restrict__ x, const float* __restrict__ wrq,
    const float* __restrict__ wrk, const float* __restrict__ wrv,
    float* __restrict__ wq, float* __restrict__ wk, float* __restrict__ wv)
{
    const int m = blockIdx.x, lane = threadIdx.x;
    float aq[8], ak[8], av[8];
#pragma unroll
    for (int r=0;r<8;r++){ aq[r]=0.f; ak[r]=0.f; av[r]=0.f; }
#pragma unroll
    for (int i=0;i<4;i++){
        const size_t d0 = i*256 + lane*4;
        float4 xv = *(const float4*)(x + (size_t)m*Dd + d0);
#pragma unroll
        for (int r=0;r<8;r++){
            float4 q4 = *(const float4*)(wrq + (size_t)r*Dd + d0);
            aq[r] += xv.x*q4.x + xv.y*q4.y + xv.z*q4.z + xv.w*q4.w;
            float4 k4 = *(const float4*)(wrk + (size_t)r*Dd + d0);
            ak[r] += xv.x*k4.x + xv.y*k4.y + xv.z*k4.z + xv.w*k4.w;
            float4 v4 = *(const float4*)(wrv + (size_t)r*Dd + d0);
            av[r] += xv.x*v4.x + xv.y*v4.y + xv.z*v4.z + xv.w*v4.w;
        }
    }
#pragma unroll
    for (int r=0;r<8;r++){
#pragma unroll
        for (int off=32;off>=1;off>>=1){
            aq[r]+=__shfl_xor(aq[r],off);
            ak[r]+=__shfl_xor(ak[r],off);
            av[r]+=__shfl_xor(av[r],off);
        }
    }
    float mq=aq[0], mk=ak[0], mv=av[0];
#pragma unroll
    for (int r=1;r<8;r++){ mq=fmaxf(mq,aq[r]); mk=fmaxf(mk,ak[r]); mv=fmaxf(mv,av[r]); }
    float eq[8], ek[8], ev[8], sq=0.f, sk=0.f, sv=0.f;
#pragma unroll
    for (int r=0;r<8;r++){
        eq[r]=expf(aq[r]-mq); sq+=eq[r];
        ek[r]=expf(ak[r]-mk); sk+=ek[r];
        ev[r]=expf(av[r]-mv); sv+=ev[r];
    }
    if (lane < 8)        wq[m*8+lane]    = eq[lane]/sq;
    else if (lane < 16)  wk[m*8+lane-8]  = ek[lane-8]/sk;
    else if (lane < 24)  wv[m*8+lane-16] = ev[lane-16]/sv;
}

// ---------------- compress: q,k,v [M,R] bf16 via MFMA ----------------
// block 128m x 64r, BK=64, double-buffered LDS + prefetch-after-barrier.
// grid m-fastest (same-m blocks share an XCD). Rows chunk-swizzled p^(r&7).
__global__ __launch_bounds__(256) void k_compress_mfma(
    const u16* __restrict__ xb, const u16* __restrict__ cnT,
    const float* __restrict__ wq, const float* __restrict__ wk, const float* __restrict__ wv,
    u16* __restrict__ qb, u16* __restrict__ kb, u16* __restrict__ vb)
{
    __shared__ __align__(16) u16 As[2][128*64];   // 2 x 16 KB
    __shared__ __align__(16) u16 Bs[2][64*64];    // 2 x 8 KB
    __shared__ float wL[3][8][128];               // 12 KB
    const int tid = threadIdx.x;
    const int lane = tid & 63, w = tid >> 6;
    const int quad = lane >> 4, l15 = lane & 15;
    const int m0 = blockIdx.x*128, r0 = blockIdx.y*64;
    for (int i = tid; i < 3*8*128; i += 256){
        const int t = i >> 10, rem = i & 1023, n = rem >> 7, ml = rem & 127;
        const float* wsrc = (t==0)? wq : (t==1)? wk : wv;
        wL[t][n][ml] = wsrc[(size_t)(m0+ml)*8 + n];
    }
    const int wm = (w&1)*64, wr = (w>>1)*32;
    const int srow = lane>>3;                 // 0..7
    const int sch  = (lane&7) ^ srow;         // swizzled source chunk
    // round t: n = t>>4, s = t&15, buffer bi = t&1
    auto stage = [&](int t){
        const int bi = t & 1;
        const int n = t >> 4, s = t & 15;
        const int d0 = s*64;
        const size_t bbase = (size_t)(n*512 + r0)*1024;
        u16* Ad = As[bi]; u16* Bd = Bs[bi];
#pragma unroll
        for (int i=0;i<4;i++)
            gld_lds16(xb + (size_t)(m0 + i*32 + w*8 + srow)*Dd + d0 + sch*8,
                      Ad + (i*32 + w*8)*64);
#pragma unroll
        for (int i=0;i<2;i++)
            gld_lds16(cnT + bbase + (size_t)(i*32 + w*8 + srow)*1024 + d0 + sch*8,
                      Bd + (i*32 + w*8)*64);
    };
    f4v accq[4][2], acck[4][2], accv[4][2], cacc[4][2];
    const f4v fz = {0.f,0.f,0.f,0.f};
#pragma unroll
    for (int mt=0;mt<4;mt++)
#pragma unroll
        for (int rt=0;rt<2;rt++){ accq[mt][rt]=fz; acck[mt][rt]=fz; accv[mt][rt]=fz; cacc[mt][rt]=fz; }
    stage(0);
    for (int t=0; t<128; t++){
        __syncthreads();                 // stage(t) complete (all waves)
        if (t+1 < 128) stage(t+1);       // prefetch into alternate buffer
        const int bi = t & 1;
        const u16* Ac = As[bi]; const u16* Bc = Bs[bi];
        s8v af[4][2], bf[2][2];
#pragma unroll
        for (int mt=0;mt<4;mt++)
#pragma unroll
            for (int kc=0;kc<2;kc++)
                af[mt][kc] = *(const s8v*)(Ac + (wm + mt*16 + l15)*64 + (((kc*4+quad) ^ (l15&7))<<3));
#pragma unroll
        for (int rt=0;rt<2;rt++)
#pragma unroll
            for (int kc=0;kc<2;kc++)
                bf[rt][kc] = *(const s8v*)(Bc + (wr + rt*16 + l15)*64 + (((kc*4+quad) ^ (l15&7))<<3));
#pragma unroll
        for (int mt=0;mt<4;mt++)
#pragma unroll
            for (int rt=0;rt<2;rt++){
                cacc[mt][rt] = __builtin_amdgcn_mfma_f32_16x16x32_bf16(af[mt][0], bf[rt][0], cacc[mt][rt], 0,0,0);
                cacc[mt][rt] = __builtin_amdgcn_mfma_f32_16x16x32_bf16(af[mt][1], bf[rt][1], cacc[mt][rt], 0,0,0);
            }
        if ((t & 15) == 15){
            const int n = t >> 4;
#pragma unroll
            for (int mt=0;mt<4;mt++){
                const int mq4 = wm + mt*16 + (quad<<2);
                f4v w0 = *(const f4v*)&wL[0][n][mq4];
                f4v w1 = *(const f4v*)&wL[1][n][mq4];
                f4v w2 = *(const f4v*)&wL[2][n][mq4];
#pragma unroll
                for (int rt=0;rt<2;rt++){
                    accq[mt][rt] += w0 * cacc[mt][rt];
                    acck[mt][rt] += w1 * cacc[mt][rt];
                    accv[mt][rt] += w2 * cacc[mt][rt];
                    cacc[mt][rt] = fz;
                }
            }
        }
    }
#pragma unroll
    for (int mt=0;mt<4;mt++)
#pragma unroll
        for (int rt=0;rt<2;rt++){
            const int rcol = r0 + wr + rt*16 + l15;
#pragma unroll
            for (int e=0;e<4;e++){
                const int m = m0 + wm + mt*16 + (quad<<2) + e;
                const size_t idx = (size_t)m*Rr + rcol;
                qb[idx] = f2bf(accq[mt][rt][e]);
                kb[idx] = f2bf(acck[mt][rt][e]);
                vb[idx] = f2bf(accv[mt][rt][e]);
            }
        }
}

// ---------------- MFMA causal flash attention ----------------
__global__ __launch_bounds__(256) void k_attn_mfma(
    const u16* __restrict__ qb, const u16* __restrict__ kb, const u16* __restrict__ vtb,
    u16* __restrict__ ab)
{
    __shared__ __align__(16) u16 Ks[64*64];
    __shared__ __align__(16) u16 Vt[64*64];
    __shared__ __align__(16) u16 Ps[4*16*64];
    const int tid = threadIdx.x;
    const int lane = tid & 63, w = tid >> 6;
    const int quad = lane >> 4, l15 = lane & 15;
    const int bh = blockIdx.x;
    const int yq = blockIdx.y;
    const int qt = (yq < 16) ? yq : (47 - yq);
    const int b = bh >> 3, h = bh & 7;
    const u16* qbase = qb + (size_t)(b*Ss)*Rr + h*DHd;
    const u16* kbase = kb + (size_t)(b*Ss)*Rr + h*DHd;
    const u16* vtbase = vtb + (size_t)bh*DHd*Ss;
    s8v qf[2];
    {
        const size_t qrow = qt*64 + w*16 + l15;
        qf[0] = *(const s8v*)(qbase + qrow*Rr + quad*8);
        qf[1] = *(const s8v*)(qbase + qrow*Rr + 32 + quad*8);
    }
    const f4v fz = {0.f,0.f,0.f,0.f};
    f4v oacc[4];
#pragma unroll
    for (int dn=0;dn<4;dn++) oacc[dn]=fz;
    float m_e[4], l_e[4];
#pragma unroll
    for (int e=0;e<4;e++){ m_e[e] = -1e30f; l_e[e] = 0.f; }
    const int srow = lane>>3;
    const int sch  = (lane&7) ^ srow;
    u16* pw = Ps + w*1024;
    for (int kt=0; kt<=qt; kt++){
        __syncthreads();
        gld_lds16(kbase + (size_t)(kt*64 + w*8 + srow)*Rr + sch*8,        Ks + w*512);
        gld_lds16(kbase + (size_t)(kt*64 + 32 + w*8 + srow)*Rr + sch*8,   Ks + 2048 + w*512);
        gld_lds16(vtbase + (size_t)(w*8 + srow)*Ss + kt*64 + sch*8,       Vt + w*512);
        gld_lds16(vtbase + (size_t)(32 + w*8 + srow)*Ss + kt*64 + sch*8,  Vt + 2048 + w*512);
        __syncthreads();
        f4v s[4];
#pragma unroll
        for (int cn=0;cn<4;cn++) s[cn]=fz;
#pragma unroll
        for (int cn=0;cn<4;cn++)
#pragma unroll
            for (int kc=0;kc<2;kc++){
                s8v bf = *(const s8v*)(Ks + (cn*16 + l15)*64 + (((kc*4 + quad) ^ (l15&7))<<3));
                s[cn] = __builtin_amdgcn_mfma_f32_16x16x32_bf16(qf[kc], bf, s[cn], 0,0,0);
            }
        if (kt == qt){
            const int qg = qt*64 + w*16 + quad*4;
            const int kg = kt*64 + l15;
#pragma unroll
            for (int cn=0;cn<4;cn++)
#pragma unroll
                for (int e=0;e<4;e++){
                    float sv = s[cn][e]*0.125f;
                    s[cn][e] = ((kg + cn*16) > (qg + e)) ? -1e30f : sv;
                }
        } else {
#pragma unroll
            for (int cn=0;cn<4;cn++)
#pragma unroll
                for (int e=0;e<4;e++) s[cn][e] *= 0.125f;
        }
        float al_e[4];
#pragma unroll
        for (int e=0;e<4;e++){
            float mx = fmaxf(fmaxf(s[0][e],s[1][e]), fmaxf(s[2][e],s[3][e]));
#pragma unroll
            for (int off=1;off<16;off<<=1) mx = fmaxf(mx, __shfl_xor(mx, off));
            const float mt = fmaxf(m_e[e], mx);
            const float al = __expf(m_e[e] - mt);
            m_e[e] = mt;
            float sum = 0.f;
#pragma unroll
            for (int cn=0;cn<4;cn++){
                float p = __expf(s[cn][e] - mt);
                s[cn][e] = p; sum += p;
            }
#pragma unroll
            for (int off=1;off<16;off<<=1) sum += __shfl_xor(sum, off);
            l_e[e] = l_e[e]*al + sum;
            al_e[e] = al;
        }
#pragma unroll
        for (int e=0;e<4;e++){
            const int row = quad*4 + e;
#pragma unroll
            for (int cn=0;cn<4;cn++){
                const int key = cn*16 + l15;
                pw[row*64 + (((key>>3) ^ (row&7))<<3) + (key&7)] = f2bf(s[cn][e]);
            }
        }
#pragma unroll
        for (int dn=0;dn<4;dn++)
#pragma unroll
            for (int e=0;e<4;e++) oacc[dn][e] *= al_e[e];
#pragma unroll
        for (int dn=0;dn<4;dn++)
#pragma unroll
            for (int kc=0;kc<2;kc++){
                s8v pf = *(const s8v*)(pw + l15*64 + (((kc*4 + quad) ^ (l15&7))<<3));
                s8v vf = *(const s8v*)(Vt + (dn*16 + l15)*64 + (((kc*4 + quad) ^ (l15&7))<<3));
                oacc[dn] = __builtin_amdgcn_mfma_f32_16x16x32_bf16(pf, vf, oacc[dn], 0,0,0);
            }
    }
    u16* abase = ab + (size_t)(b*Ss + qt*64 + w*16)*Rr + h*DHd;
#pragma unroll
    for (int e=0;e<4;e++){
        const float inv = 1.f / l_e[e];
#pragma unroll
        for (int dn=0;dn<4;dn++)
            abase[(size_t)(quad*4+e)*Rr + dn*16 + l15] = f2bf(oacc[dn][e]*inv);
    }
}

// ---------------- output router softmax weights [M,8] (ab bf16, wro fp32) ----------------
__global__ __launch_bounds__(64) void k_router_o(
    const u16* __restrict__ ab, const float* __restrict__ wro, float* __restrict__ wo)
{
    const int m = blockIdx.x, lane = threadIdx.x;
    float a[8];
#pragma unroll
    for (int r=0;r<8;r++) a[r]=0.f;
#pragma unroll
    for (int i=0;i<2;i++){
        const size_t d0 = i*256 + lane*4;
        ushort4 av4 = *(const ushort4*)(ab + (size_t)m*Rr + d0);
        float a0=bf2f(av4.x), a1=bf2f(av4.y), a2=bf2f(av4.z), a3=bf2f(av4.w);
#pragma unroll
        for (int r=0;r<8;r++){
            float4 w4 = *(const float4*)(wro + (size_t)r*Rr + d0);
            a[r] += a0*w4.x + a1*w4.y + a2*w4.z + a3*w4.w;
        }
    }
#pragma unroll
    for (int r=0;r<8;r++)
#pragma unroll
        for (int off=32;off>=1;off>>=1) a[r]+=__shfl_xor(a[r],off);
    float mx=a[0];
#pragma unroll
    for (int r=1;r<8;r++) mx=fmaxf(mx,a[r]);
    float e[8], s=0.f;
#pragma unroll
    for (int r=0;r<8;r++){ e[r]=expf(a[r]-mx); s+=e[r]; }
    if (lane < 8) wo[m*8+lane] = e[lane]/s;
}

// ---------------- expand: out [M,D] fp32 via MFMA (BK=64, dbuf, m-fast grid) ----------------
__global__ __launch_bounds__(256) void k_expand_mfma(
    const u16* __restrict__ ab, const u16* __restrict__ enT,
    const float* __restrict__ wo, float* __restrict__ out)
{
    __shared__ __align__(16) u16 As[2][128*64];
    __shared__ __align__(16) u16 Bs[2][64*64];
    __shared__ float wL[8][128];
    const int tid = threadIdx.x;
    const int lane = tid & 63, w = tid >> 6;
    const int quad = lane >> 4, l15 = lane & 15;
    const int m0 = blockIdx.x*128, dB0 = blockIdx.y*64;
    for (int i = tid; i < 8*128; i += 256){
        const int n = i >> 7, ml = i & 127;
        wL[n][ml] = wo[(size_t)(m0+ml)*8 + n];
    }
    const int wm = (w&1)*64, wr = (w>>1)*32;
    const int srow = lane>>3;
    const int sch  = (lane&7) ^ srow;
    // round t: n = t>>3, s = t&7, buffer bi = t&1
    auto stage = [&](int t){
        const int bi = t & 1;
        const int n = t >> 3, s = t & 7;
        const int r0k = s*64;
        const size_t bbase = (size_t)(n*1024 + dB0)*512;
        u16* Ad = As[bi]; u16* Bd = Bs[bi];
#pragma unroll
        for (int i=0;i<4;i++)
            gld_lds16(ab + (size_t)(m0 + i*32 + w*8 + srow)*Rr + r0k + sch*8,
                      Ad + (i*32 + w*8)*64);
#pragma unroll
        for (int i=0;i<2;i++)
            gld_lds16(enT + bbase + (size_t)(i*32 + w*8 + srow)*512 + r0k + sch*8,
                      Bd + (i*32 + w*8)*64);
    };
    f4v acc[4][2], cacc[4][2];
    const f4v fz = {0.f,0.f,0.f,0.f};
#pragma unroll
    for (int mt=0;mt<4;mt++)
#pragma unroll
        for (int rt=0;rt<2;rt++){ acc[mt][rt]=fz; cacc[mt][rt]=fz; }
    stage(0);
    for (int t=0; t<64; t++){
        __syncthreads();
        if (t+1 < 64) stage(t+1);
        const int bi = t & 1;
        const u16* Ac = As[bi]; const u16* Bc = Bs[bi];
        s8v af[4][2], bf[2][2];
#pragma unroll
        for (int mt=0;mt<4;mt++)
#pragma unroll
            for (int kc=0;kc<2;kc++)
                af[mt][kc] = *(const s8v*)(Ac + (wm + mt*16 + l15)*64 + (((kc*4+quad) ^ (l15&7))<<3));
#pragma unroll
        for (int rt=0;rt<2;rt++)
#pragma unroll
            for (int kc=0;kc<2;kc++)
                bf[rt][kc] = *(const s8v*)(Bc + (wr + rt*16 + l15)*64 + (((kc*4+quad) ^ (l15&7))<<3));
#pragma unroll
        for (int mt=0;mt<4;mt++)
#pragma unroll
            for (int rt=0;rt<2;rt++){
                cacc[mt][rt] = __builtin_amdgcn_mfma_f32_16x16x32_bf16(af[mt][0], bf[rt][0], cacc[mt][rt], 0,0,0);
                cacc[mt][rt] = __builtin_amdgcn_mfma_f32_16x16x32_bf16(af[mt][1], bf[rt][1], cacc[mt][rt], 0,0,0);
            }
        if ((t & 7) == 7){
            const int n = t >> 3;
#pragma unroll
            for (int mt=0;mt<4;mt++){
                const int mq4 = wm + mt*16 + (quad<<2);
                f4v w0 = *(const f4v*)&wL[n][mq4];
#pragma unroll
                for (int rt=0;rt<2;rt++){
                    acc[mt][rt] += w0 * cacc[mt][rt];
                    cacc[mt][rt] = fz;
                }
            }
        }
    }
#pragma unroll
    for (int mt=0;mt<4;mt++)
#pragma unroll
        for (int rt=0;rt<2;rt++){
            const int dcol = dB0 + wr + rt*16 + l15;
#pragma unroll
            for (int e=0;e<4;e++){
                const int m = m0 + wm + mt*16 + (quad<<2) + e;
                out[(size_t)m*Dd + dcol] = acc[mt][rt][e];   // fp32 output
            }
        }
}

extern "C" void kernel_launch(void* const* d_in, const int* in_sizes, int n_in,
                              void* d_out, int out_size, void* d_ws, size_t ws_size,
                              hipStream_t stream) {
    (void)in_sizes; (void)n_in; (void)out_size; (void)ws_size;
    const float* x   = (const float*)d_in[0];
    // d_in[1] = causal mask — deterministic, unused
    const float* cn  = (const float*)d_in[2];
    const float* en  = (const float*)d_in[3];
    const float* wrq = (const float*)d_in[4];
    const float* wrk = (const float*)d_in[5];
    const float* wrv = (const float*)d_in[6];
    const float* wro = (const float*)d_in[7];

    float* ws = (float*)d_ws;
    float* wq = ws;                          // [M,8] f32
    float* wk = wq + Mm*8;
    float* wv = wk + Mm*8;
    float* wo = wv + Mm*8;
    u16* xb  = (u16*)(wo + Mm*8);            // [M,D] bf16
    u16* qb  = xb + (size_t)Mm*Dd;           // [M,R] bf16
    u16* kb  = qb + (size_t)Mm*Rr;
    u16* vb  = kb + (size_t)Mm*Rr;
    u16* ab  = vb + (size_t)Mm*Rr;           // attention out [M,R] bf16
    u16* cnT = ab + (size_t)Mm*Rr;           // [8][R][D] bf16
    u16* enT = cnT + (size_t)8*Rr*Dd;        // [8][D][R] bf16
    u16* vtb = enT + (size_t)8*Dd*Rr;        // [BH][DH][S] bf16

    k_f2b<<<Mm*Dd/1024, 256, 0, stream>>>(x, xb);
    k_transpose_f2b<<<dim3(Dd/64, Rr/64, 8), 256, 0, stream>>>(cn, cnT, Dd, Rr);
    k_transpose_f2b<<<dim3(Rr/64, Dd/64, 8), 256, 0, stream>>>(en, enT, Rr, Dd);
    k_router_qkv<<<Mm, 64, 0, stream>>>(x, wrq, wrk, wrv, wq, wk, wv);
    // m-fastest grid: same-m blocks land on the same XCD (id % 8 == m % 8)
    k_compress_mfma<<<dim3(Mm/128, Rr/64), 256, 0, stream>>>(xb, cnT, wq, wk, wv, qb, kb, vb);
    k_transpose_v<<<dim3(Ss/64, Bb*Hh), 256, 0, stream>>>(vb, vtb);
    k_attn_mfma<<<dim3(Bb*Hh, Ss/64), 256, 0, stream>>>(qb, kb, vtb, ab);
    k_router_o<<<Mm, 64, 0, stream>>>(ab, wro, wo);
    k_expand_mfma<<<dim3(Mm/128, Dd/64), 256, 0, stream>>>(ab, enT, wo, (float*)d_out);
}